// Round 12
// baseline (199.171 us; speedup 1.0000x reference)
//
#include <hip/hip_runtime.h>
#include <hip/hip_bf16.h>

// ---------------------------------------------------------------------------
// Transformer block: LN(h + (softmax(mask(QK^T))V)Wo + sigmoid(hW1)*(hW2))
// B=2 S=2048 D_MODEL=1024 H=16 DH=64.  All heavy math in bf16 MFMA.
// ---------------------------------------------------------------------------

typedef short bf16x8 __attribute__((ext_vector_type(8)));   // 8 bf16 = 4 VGPR
typedef float f32x4  __attribute__((ext_vector_type(4)));
typedef float f32x16 __attribute__((ext_vector_type(16)));
typedef unsigned int u32x4 __attribute__((ext_vector_type(4)));

typedef const __attribute__((address_space(1))) void* gas_cvp;
typedef __attribute__((address_space(3))) void* las_vp;

__device__ __forceinline__ void gload_lds16(const void* g, void* l) {
  __builtin_amdgcn_global_load_lds((gas_cvp)g, (las_vp)l, 16, 0, 0);
}

__device__ __forceinline__ short f2bf(float f) {
  __hip_bfloat16 h = __float2bfloat16(f);
  return *reinterpret_cast<short*>(&h);
}
__device__ __forceinline__ float bf2f(short s) {
  unsigned u = ((unsigned)(unsigned short)s) << 16;
  return __builtin_bit_cast(float, u);
}

#if __has_builtin(__builtin_amdgcn_exp2f)
#define EXP2(x) __builtin_amdgcn_exp2f(x)
#else
#define EXP2(x) exp2f(x)
#endif

constexpr int BATCH = 2;
constexpr int SEQ   = 2048;
constexpr int NH    = 16;
constexpr int MROWS = BATCH * SEQ;   // 4096
constexpr int NSPLIT = 2;            // K-direction split for occupancy
constexpr int KSPL   = SEQ / NSPLIT; // keys per split = 1024
constexpr int RH     = MROWS * NH;   // rowheads = 65536

// ------------------------------- small kernels -----------------------------

__global__ __launch_bounds__(256) void cvt_bf16(const float* __restrict__ src,
                                                short* __restrict__ dst, int n4) {
  int i = blockIdx.x * 256 + threadIdx.x;
  if (i >= n4) return;
  float4 v = reinterpret_cast<const float4*>(src)[i];
  short4 o;
  o.x = f2bf(v.x); o.y = f2bf(v.y); o.z = f2bf(v.z); o.w = f2bf(v.w);
  reinterpret_cast<short4*>(dst)[i] = o;
}

// six 1024x1024 fp32->bf16 transposes in one launch (blockIdx.z selects).
// dst row = n*mul + add  (mul=2 interleaves W1/W2 for the fused-GLU GEMM).
struct WtA {
  const float* s[6];
  short* d[6];
  int st[6];
  int mul[6];
  int add[6];
};
__global__ __launch_bounds__(256) void wtrans6(WtA a) {
  __shared__ float tile[32][33];
  const float* __restrict__ src = a.s[blockIdx.z];
  short* __restrict__ dst = a.d[blockIdx.z];
  const int stride = a.st[blockIdx.z];
  const int mul = a.mul[blockIdx.z], add = a.add[blockIdx.z];
  const int tx = threadIdx.x & 31, ty = threadIdx.x >> 5;   // 32 x 8
  const int n0 = blockIdx.x * 32, k0 = blockIdx.y * 32;
  #pragma unroll
  for (int i = 0; i < 32; i += 8)
    tile[ty + i][tx] = src[(size_t)(k0 + ty + i) * stride + n0 + tx];
  __syncthreads();
  #pragma unroll
  for (int i = 0; i < 32; i += 8)
    dst[(size_t)((n0 + ty + i) * mul + add) * 1024 + k0 + tx] = f2bf(tile[tx][ty + i]);
}

// V-part of QKV [4096][3072] (cols 2048..3071) -> VT [2][1024][2048] bf16
__global__ __launch_bounds__(256) void vtrans(const short* __restrict__ qkv,
                                              short* __restrict__ vt) {
  __shared__ short tile[32][33];
  const int tx = threadIdx.x & 31, ty = threadIdx.x >> 5;
  const int s0 = blockIdx.x * 32, d0 = blockIdx.y * 32, b = blockIdx.z;
  #pragma unroll
  for (int i = 0; i < 32; i += 8)
    tile[ty + i][tx] = qkv[(size_t)(b * SEQ + s0 + ty + i) * 3072 + 2048 + d0 + tx];
  __syncthreads();
  #pragma unroll
  for (int i = 0; i < 32; i += 8)
    vt[(size_t)(b * 1024 + d0 + ty + i) * SEQ + s0 + tx] = tile[tx][ty + i];
}

// ball = [bq | bkv | interleaved {b1,b2}]  (5120 floats)
__global__ void pack_bias(const float* __restrict__ bq, const float* __restrict__ bkv,
                          const float* __restrict__ b1, const float* __restrict__ b2,
                          float* __restrict__ ball) {
  int i = blockIdx.x * 256 + threadIdx.x;
  if (i < 1024) ball[i] = bq[i];
  else if (i < 3072) ball[i] = bkv[i - 1024];
  else if (i < 4096) {
    const int j = i - 3072;
    ball[3072 + 2 * j] = b1[j];
    ball[3072 + 2 * j + 1] = b2[j];
  }
}

__device__ __forceinline__ bool mask_at(const void* mp, int idx, int flag) {
  if (flag == 1) return ((const int*)mp)[idx] != 0;
  if (flag == 2) return ((const float*)mp)[idx] != 0.f;
  return ((const unsigned char*)mp)[idx] != 0;
}

// mask -> additive bias in exp2 domain, with inline dtype detection (mask bool
// may arrive as u8 / i32 / f32). Static-max softmax: fixed -8 shift folded in.
__global__ __launch_bounds__(256) void premask(const void* __restrict__ msk,
                                               float* __restrict__ mbL) {
  __shared__ int si, sf;
  const unsigned* m = (const unsigned*)msk;
  if (threadIdx.x == 0) { si = 1; sf = 1; }
  __syncthreads();
  bool oki = true, okf = true;
  for (int i = threadIdx.x; i < 1024; i += 256) {   // first 4096 bytes, in-bounds always
    unsigned v = m[i];
    oki = oki && (v <= 1u);
    okf = okf && (v == 0u || v == 0x3F800000u);
  }
  if (!oki) si = 0;
  if (!okf) sf = 0;
  __syncthreads();
  const int flag = si ? 1 : (sf ? 2 : 0);
  int i = blockIdx.x * 256 + threadIdx.x;
  if (i < MROWS) mbL[i] = mask_at(msk, i, flag) ? -1.442695e9f : -8.0f;
}

// ------------------------------- GEMM (Wo) ---------------------------------
// m97 structure + R11 zero-conflict source-swizzle, BK=64.  BN=64 (2/CU for
// the N=1024 Wo shape).
template <int BN>
__global__ __launch_bounds__(256) void gemm_bf16(const short* __restrict__ A,
                                                 const short* __restrict__ BT,
                                                 const float* __restrict__ bias,
                                                 short* __restrict__ outp, int N) {
  constexpr int NF = BN / 64;
  __shared__ short Alds[128 * 64];
  __shared__ short Blds[BN * 64];
  const int tid = threadIdx.x;
  const int w = tid >> 6, l = tid & 63, lr = l & 15;
  const int wr = w >> 1, wc = w & 1;
  const int bm = blockIdx.y, bn = blockIdx.x;

  f32x4 acc[4][2 * NF] = {};

  const int srow = tid >> 3;
  const int schunk = (tid & 7) ^ (srow & 7);
  const short* Ab = A  + (size_t)(bm * 128 + srow) * 1024 + schunk * 8;
  const short* Bb = BT + (size_t)(bn * BN + srow) * 1024 + schunk * 8;

  const int cg = (l >> 4) ^ (l & 3), fl = (l >> 2) & 1;
  const short* ard[2] = { &Alds[(wr * 64 + lr) * 64 + cg * 8 + fl * 32],
                          &Alds[(wr * 64 + lr) * 64 + cg * 8 + 32 - fl * 32] };
  const short* brd[2] = { &Blds[(wc * (BN / 2) + lr) * 64 + cg * 8 + fl * 32],
                          &Blds[(wc * (BN / 2) + lr) * 64 + cg * 8 + 32 - fl * 32] };

  for (int kt = 0; kt < 16; ++kt) {
    const int kb = kt * 64;
    __syncthreads();
    #pragma unroll
    for (int q = 0; q < 4; ++q)
      gload_lds16(Ab + (size_t)q * 32 * 1024 + kb, &Alds[q * 2048 + tid * 8]);
    #pragma unroll
    for (int q = 0; q < BN / 32; ++q)
      gload_lds16(Bb + (size_t)q * 32 * 1024 + kb, &Blds[q * 2048 + tid * 8]);
    asm volatile("s_waitcnt vmcnt(0)" ::: "memory");
    __syncthreads();

    #pragma unroll
    for (int s = 0; s < 2; ++s) {
      bf16x8 af[4], bfr[2 * NF];
      #pragma unroll
      for (int m = 0; m < 4; ++m)
        af[m] = *reinterpret_cast<const bf16x8*>(ard[s] + m * 16 * 64);
      #pragma unroll
      for (int n = 0; n < 2 * NF; ++n)
        bfr[n] = *reinterpret_cast<const bf16x8*>(brd[s] + n * 16 * 64);
      #pragma unroll
      for (int m = 0; m < 4; ++m)
        #pragma unroll
        for (int n = 0; n < 2 * NF; ++n)
          acc[m][n] = __builtin_amdgcn_mfma_f32_16x16x32_bf16(af[m], bfr[n], acc[m][n], 0, 0, 0);
    }
  }

  const int g = l >> 4;
  #pragma unroll
  for (int m = 0; m < 4; ++m) {
    const int row = bm * 128 + wr * 64 + m * 16 + g * 4;
    #pragma unroll
    for (int n = 0; n < 2 * NF; ++n) {
      const int col = bn * BN + wc * (BN / 2) + n * 16 + lr;
      const float bv = bias[col];
      #pragma unroll
      for (int r = 0; r < 4; ++r)
        outp[(size_t)(row + r) * N + col] = f2bf(acc[m][n][r] + bv);
    }
  }
}

// --------------------- fused QKV+GLU GEMM, deep pipeline --------------------
// BM=128 BN=256 BK=64, 512 threads (8 waves 2Mx4N, per-wave C 64x64).
// T3/T4: 3-LDS-buffer ring (144KB dynamic), per sub-phase (kstep, K=32):
//   stage k-half of tile t+2 (3 gload_lds) -> 8 ds_read_b128 -> 16 MFMA
//   -> s_waitcnt vmcnt(9) (counted, never 0 in steady state) -> barrier.
// Stages stay 4 sub-phases (~1300 cyc) in flight: HBM latency fully hidden.
// LDS layout: per k-half plane [rows][4 chunks of 16B], chunk stored at
// c ^ ((row>>1)&3): linear gload dests (G21, source pre-swizzled), and frag
// reads land 2 lanes/bank (free, m136).
// Epilogue: bn<12 -> QKV bf16; bn>=12 -> GLU parity trick -> X1.
__global__ __launch_bounds__(512) void gemm_qkvglu8(const short* __restrict__ A,
                                                    const short* __restrict__ BT,
                                                    const float* __restrict__ bias,
                                                    short* __restrict__ qkv,
                                                    short* __restrict__ x1) {
  extern __shared__ short lds[];   // 3 bufs x 24576 shorts (A 8192 | B 16384)
  const int tid = threadIdx.x;
  const int w = tid >> 6, l = tid & 63, lr = l & 15, g = l >> 4;
  const int wr = w >> 2, wc = w & 3;          // 2 x 4 waves
  // bijective XCD swizzle (640 % 8 == 0), bn-major for B-panel L2 reuse
  const int idx = blockIdx.x;
  const int swz = (idx & 7) * 80 + (idx >> 3);
  const int bn = swz / 32, bm = swz % 32;

  // ---- staging maps (per-thread constants) ----
  // A k-half plane: 512 slots (row=tid>>2, stored chunk=tid&3), 1 load.
  // B k-half plane: 1024 slots (rows tid>>2 and 128+tid>>2), 2 loads.
  const int arow = tid >> 2, ac2 = tid & 3;
  const int lc8 = (ac2 ^ ((arow >> 1) & 3)) * 8;    // same for B rows (+128)
  const short* aSrc = A + (size_t)(bm * 128 + arow) * 1024 + lc8;
  const short* bSrc = BT + (size_t)(bn * 256 + arow) * 1024 + lc8;
  short* aDst = lds + tid * 8;
  short* bDst = lds + 8192 + tid * 8;

  auto stageKhalf = [&](int t, int s) {
    const int buf = (t % 3) * 24576;
    const int kof = t * 64 + s * 32;
    gload_lds16(aSrc + kof, aDst + buf + s * 4096);
    gload_lds16(bSrc + kof, bDst + buf + s * 8192);
    gload_lds16(bSrc + (size_t)128 * 1024 + kof, bDst + buf + s * 8192 + 4096);
  };

  // ---- per-lane frag read bases (2-way bank access) ----
  const int cg8 = (g ^ ((lr >> 1) & 3)) * 8;
  const short* aRd = lds + (wr * 64 + lr) * 32 + cg8;          // +buf+s*4096+m*512
  const short* bRd = lds + 8192 + (wc * 64 + lr) * 32 + cg8;   // +buf+s*8192+n*512

  f32x4 acc[4][4] = {};

  // ---- prologue: tiles 0 and 1 fully staged; oldest k-half forced landed ----
  stageKhalf(0, 0); stageKhalf(0, 1); stageKhalf(1, 0); stageKhalf(1, 1);
  asm volatile("s_waitcnt vmcnt(9)" ::: "memory");
  __syncthreads();

  for (int t = 0; t < 16; ++t) {
    const int buf = (t % 3) * 24576;
    #pragma unroll
    for (int s = 0; s < 2; ++s) {
      if (t + 2 < 16) stageKhalf(t + 2, s);
      bf16x8 af[4], bfv[4];
      #pragma unroll
      for (int m = 0; m < 4; ++m)
        af[m] = *reinterpret_cast<const bf16x8*>(aRd + buf + s * 4096 + m * 512);
      #pragma unroll
      for (int n = 0; n < 4; ++n)
        bfv[n] = *reinterpret_cast<const bf16x8*>(bRd + buf + s * 8192 + n * 512);
      __builtin_amdgcn_s_setprio(1);
      #pragma unroll
      for (int m = 0; m < 4; ++m)
        #pragma unroll
        for (int n = 0; n < 4; ++n)
          acc[m][n] = __builtin_amdgcn_mfma_f32_16x16x32_bf16(af[m], bfv[n], acc[m][n], 0, 0, 0);
      __builtin_amdgcn_s_setprio(0);
      // counted waits: drain exactly through the k-half needed next sub-phase
      if (t <= 13) {
        asm volatile("s_waitcnt vmcnt(9)" ::: "memory");
        __syncthreads();
      } else if (t == 14) {
        if (s == 0) asm volatile("s_waitcnt vmcnt(6)" ::: "memory");
        else        asm volatile("s_waitcnt vmcnt(3)" ::: "memory");
        __syncthreads();
      } else {
        if (s == 0) {
          asm volatile("s_waitcnt vmcnt(0)" ::: "memory");
          __syncthreads();
        }
      }
    }
  }

  // ---- epilogue ----
  const bool isGlu = (bn >= 12);
  #pragma unroll
  for (int m = 0; m < 4; ++m) {
    const int row = bm * 128 + wr * 64 + m * 16 + g * 4;
    #pragma unroll
    for (int n = 0; n < 4; ++n) {
      const int col = bn * 256 + wc * 64 + n * 16 + lr;
      const float bv = bias[col];
      #pragma unroll
      for (int r = 0; r < 4; ++r) {
        const float v = acc[m][n][r] + bv;
        if (!isGlu) {
          qkv[(size_t)(row + r) * 3072 + col] = f2bf(v);
        } else {
          // interleaved cols: even lane = x1, odd neighbor = x2
          const float vp = __shfl_xor(v, 1);
          if (!(lr & 1))
            x1[(size_t)(row + r) * 1024 + ((col - 3072) >> 1)] =
                f2bf(vp / (1.f + __expf(-v)));
        }
      }
    }
  }
}

// ------------------------------- attention v8 -------------------------------
// Swapped-operand 32x32x16, 2-way K-split, KB=64, double-buffer granule-padded
// LDS with reg staging and ONE barrier per tile.  Static-max softmax,
// permlane32_swap P redistribution, setprio on MFMA clusters.
constexpr int KB = 64;               // keys per tile
constexpr int KSLOT = 8 * 66;        // K granule-major [8][66] 16B slots
constexpr int VSLOT = 8 * 66;        // V^T granule-major [8][66]

__global__ __launch_bounds__(256) void attn_kernel(const short* __restrict__ qkv,
                                                   const short* __restrict__ vt,
                                                   const float* __restrict__ mbL,
                                                   short* __restrict__ opart,
                                                   float* __restrict__ spart) {
  __shared__ short Kl[2][KSLOT * 8];   // 2 x 8.25 KB
  __shared__ short Vl[2][VSLOT * 8];   // 2 x 8.25 KB
  __shared__ float mb[KSPL];           // 4 KB mask bias (log2 domain, -8 shift)

  const int tid = threadIdx.x;
  const int w = tid >> 6, lane = tid & 63, ql = lane & 31, hi = lane >> 5;
  const int sp = blockIdx.x & (NSPLIT - 1), qb = blockIdx.x / NSPLIT;
  const int h = blockIdx.y, b = blockIdx.z;
  const int qrow = qb * 128 + w * 32 + ql;
  const int kofs = sp * KSPL;

  // ---- hoist Q fragments (B-operand: lane q holds Q[q][c*16 + hi*8 + j]) ----
  bf16x8 qf[4];
  {
    const short* qp = qkv + (size_t)(b * SEQ + qrow) * 3072 + h * 64;
    #pragma unroll
    for (int c = 0; c < 4; ++c)
      qf[c] = *reinterpret_cast<const bf16x8*>(qp + c * 16 + hi * 8);
  }

  // ---- staging maps (per-thread constants) ----
  const short* gkbase = qkv + (size_t)(b * SEQ + kofs) * 3072 + 1024 + h * 64
                        + (size_t)(tid >> 3) * 3072 + (tid & 7) * 8;
  const short* gvbase = vt + ((size_t)(b * 1024 + h * 64) + (tid >> 3)) * SEQ + kofs
                        + (tid & 7) * 8;
  short* kwr = &Kl[0][((tid & 7) * 66 + (tid >> 3)) * 8];
  short* vwr = &Vl[0][((tid & 7) * 66 + (tid >> 3)) * 8];

  u32x4 kreg0, kreg1, vreg0, vreg1;
  auto loadTile = [&](int kt) {
    const short* gk = gkbase + (size_t)kt * KB * 3072;
    kreg0 = *reinterpret_cast<const u32x4*>(gk);
    kreg1 = *reinterpret_cast<const u32x4*>(gk + 32 * 3072);
    const short* gv = gvbase + kt * KB;
    vreg0 = *reinterpret_cast<const u32x4*>(gv);
    vreg1 = *reinterpret_cast<const u32x4*>(gv + 32 * SEQ);
  };
  auto writeTile = [&](int buf) {
    short* kd = kwr + buf * KSLOT * 8;
    *reinterpret_cast<u32x4*>(kd)          = kreg0;   // compiler waits vmcnt here
    *reinterpret_cast<u32x4*>(kd + 32 * 8) = kreg1;
    short* vd = vwr + buf * VSLOT * 8;
    *reinterpret_cast<u32x4*>(vd)          = vreg0;
    *reinterpret_cast<u32x4*>(vd + 32 * 8) = vreg1;
  };

  float s_run = 0.f;
  f32x16 oacc0 = {}, oacc1 = {};

  // ---- prologue: mask bias (4KB, all waves) + tile 0 ----
  gload_lds16(mbL + b * SEQ + kofs + tid * 4, &mb[tid * 4]);
  loadTile(0);
  writeTile(0);
  __syncthreads();

  // per-lane LDS read bases (constant; reads use +imm offsets)
  const short* krd = &Kl[0][(hi * 66 + ql) * 8];
  const short* vrd = &Vl[0][(hi * 66 + ql) * 8];

  constexpr int NT = KSPL / KB;   // 16
  for (int kt = 0; kt < NT; ++kt) {
    const int cur = kt & 1;
    if (kt + 1 < NT) loadTile(kt + 1);   // HBM latency hides under compute(t)
    const short* Kb = krd + cur * KSLOT * 8;
    const short* Vb = vrd + cur * VSLOT * 8;

    #pragma unroll
    for (int t2 = 0; t2 < 2; ++t2) {
      // QK^T: S[k][q]
      f32x16 sc = {};
      __builtin_amdgcn_s_setprio(1);
      #pragma unroll
      for (int c = 0; c < 4; ++c) {
        bf16x8 kf = *reinterpret_cast<const bf16x8*>(Kb + (c * 132 + t2 * 32) * 8);
        sc = __builtin_amdgcn_mfma_f32_32x32x16_bf16(kf, qf[c], sc, 0, 0, 0);
      }
      __builtin_amdgcn_s_setprio(0);
      // p = exp2(score*scale*log2e + bias)   (bias = mask? -1.4e9 : -8)
      float p[16];
      #pragma unroll
      for (int u = 0; u < 4; ++u) {
        float4 m4 = *reinterpret_cast<const float4*>(&mb[kt * KB + t2 * 32 + u * 8 + hi * 4]);
        p[4 * u + 0] = EXP2(fmaf(sc[4 * u + 0], 0.18033688f, m4.x));   // 0.125*log2e
        p[4 * u + 1] = EXP2(fmaf(sc[4 * u + 1], 0.18033688f, m4.y));
        p[4 * u + 2] = EXP2(fmaf(sc[4 * u + 2], 0.18033688f, m4.z));
        p[4 * u + 3] = EXP2(fmaf(sc[4 * u + 3], 0.18033688f, m4.w));
      }
      // partial-sum tree (cross-lane deferred to epilogue)
      {
        float a0 = (p[0] + p[1]) + (p[2] + p[3]);
        float a1 = (p[4] + p[5]) + (p[6] + p[7]);
        float a2 = (p[8] + p[9]) + (p[10] + p[11]);
        float a3 = (p[12] + p[13]) + (p[14] + p[15]);
        s_run += (a0 + a1) + (a2 + a3);
      }
      // pack P -> bf16 pairs; permlane32_swap redistributes across half-waves
      unsigned P[8];
      #pragma unroll
      for (int j = 0; j < 8; ++j)
        asm("v_cvt_pk_bf16_f32 %0, %1, %2" : "=v"(P[j]) : "v"(p[2 * j]), "v"(p[2 * j + 1]));
      asm("v_permlane32_swap_b32 %0, %1" : "+v"(P[0]), "+v"(P[2]));
      asm("v_permlane32_swap_b32 %0, %1" : "+v"(P[1]), "+v"(P[3]));
      asm("v_permlane32_swap_b32 %0, %1" : "+v"(P[4]), "+v"(P[6]));
      asm("v_permlane32_swap_b32 %0, %1" : "+v"(P[5]), "+v"(P[7]));
      u32x4 c0 = { P[0], P[1], P[2], P[3] };
      u32x4 c1 = { P[4], P[5], P[6], P[7] };
      bf16x8 pf[2] = { __builtin_bit_cast(bf16x8, c0), __builtin_bit_cast(bf16x8, c1) };

      // PV: O^T[d][q] += V^T[d][k] P[k][q]
      __builtin_amdgcn_s_setprio(1);
      #pragma unroll
      for (int ch = 0; ch < 2; ++ch) {
        const int gb = (t2 * 4 + ch * 2) * 66;
        bf16x8 v0 = *reinterpret_cast<const bf16x8*>(Vb + gb * 8);
        bf16x8 v1 = *reinterpret_cast<const bf16x8*>(Vb + (gb + 32) * 8);
        oacc0 = __builtin_amdgcn_mfma_f32_32x32x16_bf16(v0, pf[ch], oacc0, 0, 0, 0);
        oacc1 = __builtin_amdgcn_mfma_f32_32x32x16_bf16(v1, pf[ch], oacc1, 0, 0, 0);
      }
      __builtin_amdgcn_s_setprio(0);
    }

    if (kt + 1 < NT) {
      writeTile(cur ^ 1);   // cur^1 readers finished at end of tile kt-1
      __syncthreads();      // writes visible before tile kt+1 reads
    }
  }

  // ---- epilogue: finish sum across half-waves, store unnormalized O + s ----
  const float sT = s_run + __shfl_xor(s_run, 32);
  const size_t obase = (size_t)sp * RH * 64 + (size_t)(b * SEQ + qrow) * 1024 + h * 64;
  #pragma unroll
  for (int dt = 0; dt < 2; ++dt) {
    #pragma unroll
    for (int u = 0; u < 4; ++u) {
      short4 st;
      const f32x16& oa = dt ? oacc1 : oacc0;
      st.x = f2bf(oa[4 * u + 0]);
      st.y = f2bf(oa[4 * u + 1]);
      st.z = f2bf(oa[4 * u + 2]);
      st.w = f2bf(oa[4 * u + 3]);
      *reinterpret_cast<short4*>(&opart[obase + dt * 32 + u * 8 + hi * 4]) = st;
    }
  }
  if (hi == 0)
    spart[sp * RH + (b * SEQ + qrow) * NH + h] = sT;
}

// merge K-splits: att = sum(O_s) / sum(s_s)   (same fixed shift cancels)
__global__ __launch_bounds__(256) void attn_merge(const short* __restrict__ opart,
                                                  const float* __restrict__ spart,
                                                  short* __restrict__ att) {
  const int idx = blockIdx.x * 256 + threadIdx.x;   // RH*8 = 524288
  const int rh = idx >> 3;
  const size_t base = (size_t)rh * 64 + (idx & 7) * 8;
  float acc[8] = {};
  float ss = 0.f;
  #pragma unroll
  for (int s = 0; s < NSPLIT; ++s) {
    bf16x8 o = *reinterpret_cast<const bf16x8*>(&opart[(size_t)s * RH * 64 + base]);
    #pragma unroll
    for (int j = 0; j < 8; ++j) acc[j] += bf2f(o[j]);
    ss += spart[s * RH + rh];
  }
  const float inv = 1.f / ss;
  bf16x8 r;
  #pragma unroll
  for (int j = 0; j < 8; ++j) r[j] = f2bf(acc[j] * inv);
  *reinterpret_cast<bf16x8*>(&att[base]) = r;
}

// -------------------------- residual + LayerNorm ----------------------------
__global__ __launch_bounds__(256) void ln_kernel(const float* __restrict__ h,
                                                 const short* __restrict__ ao,
                                                 const short* __restrict__ gl,
                                                 const float* __restrict__ gamma,
                                                 const float* __restrict__ beta,
                                                 float* __restrict__ out) {
  const int row = blockIdx.x;
  const size_t base = (size_t)row * 1024;
  const int t = threadIdx.x;
  __shared__ float red[4];
  float x[4];
  #pragma unroll
  for (int j = 0; j < 4; ++j) {
    const int c = t + j * 256;
    x[j] = h[base + c] + bf2f(ao[base + c]) + bf2f(gl[base + c]);
  }
  float s = x[0] + x[1] + x[2] + x[3];
  #pragma unroll
  for (int d = 1; d < 64; d <<= 1) s += __shfl_xor(s, d);
  if ((t & 63) == 0) red[t >> 6] = s;
  __syncthreads();
  const float mu = (red[0] + red[1] + red[2] + red[3]) * (1.f / 1024.f);
  __syncthreads();
  float vs = 0.f;
  #pragma unroll
  for (int j = 0; j < 4; ++j) { const float dx = x[j] - mu; vs += dx * dx; }
  #pragma unroll
  for (int d = 1; d < 64; d <<= 1) vs += __shfl_xor(vs, d);
  if ((t & 63) == 0) red[t >> 6] = vs;
  __syncthreads();
  const float var = (red[0] + red[1] + red[2] + red[3]) * (1.f / 1024.f);
  const float rs = rsqrtf(var + 1e-6f);
  #pragma unroll
  for (int j = 0; j < 4; ++j) {
    const int c = t + j * 256;
    out[base + c] = (x[j] - mu) * rs * gamma[c] + beta[c];
  }
}

// ------------------------------- launcher ----------------------------------

extern "C" void kernel_launch(void* const* d_in, const int* in_sizes, int n_in,
                              void* d_out, int out_size, void* d_ws, size_t ws_size,
                              hipStream_t stream) {
  const float* h   = (const float*)d_in[0];
  const void*  msk = d_in[1];
  const float* Wq  = (const float*)d_in[2];
  const float* bq  = (const float*)d_in[3];
  const float* Wkv = (const float*)d_in[4];
  const float* bkv = (const float*)d_in[5];
  const float* Wo  = (const float*)d_in[6];
  const float* bo  = (const float*)d_in[7];
  const float* W1  = (const float*)d_in[8];
  const float* b1  = (const float*)d_in[9];
  const float* W2  = (const float*)d_in[10];
  const float* b2  = (const float*)d_in[11];
  const float* lng = (const float*)d_in[12];
  const float* lnb = (const float*)d_in[13];
  float* out = (float*)d_out;

  char* ws = (char*)d_ws;
  size_t off = 0;
  auto alloc = [&](size_t bytes) {
    char* p = ws + off;
    off += (bytes + 255) & ~(size_t)255;
    return p;
  };
  short* X     = (short*)alloc((size_t)MROWS * 1024 * 2);   // h in bf16
  short* WALL  = (short*)alloc((size_t)5120 * 1024 * 2);    // [Wq|Wkv|W1/W2 ilv]^T
  short* WoT   = (short*)alloc((size_t)1024 * 1024 * 2);
  float* ball  = (float*)alloc(5120 * 4);
  float* MBL   = (float*)alloc((size_t)MROWS * 4);          // mask bias (log2 dom)
  short* QKV   = (short*)alloc((size_t)MROWS * 3072 * 2);
  short* VT    = (short*)alloc((size_t)BATCH * 1024 * SEQ * 2);  // V transposed
  short* ATT   = (short*)alloc((size_t)MROWS * 1024 * 2);
  short* X1    = (short*)alloc((size_t)MROWS * 1024 * 2);   // GLU result bf16
  short* AO    = (short*)alloc((size_t)MROWS * 1024 * 2);   // attention proj bf16
  short* OP    = (short*)alloc((size_t)NSPLIT * RH * 64 * 2);  // partial O (unnorm)
  float* SP    = (float*)alloc((size_t)NSPLIT * RH * 4);       // partial sums
  if (off > ws_size) return;  // workspace too small: bail visibly

  // allow 144KB dynamic LDS for the deep-pipelined GEMM (idempotent, host-side)
  hipFuncSetAttribute(reinterpret_cast<const void*>(gemm_qkvglu8),
                      hipFuncAttributeMaxDynamicSharedMemorySize, 3 * 24576 * 2);

  cvt_bf16<<<4096, 256, 0, stream>>>(h, X, MROWS * 1024 / 4);
  WtA wa;
  wa.s[0] = Wq;          wa.d[0] = WALL;                wa.st[0] = 1024;  wa.mul[0] = 1; wa.add[0] = 0;
  wa.s[1] = Wkv;         wa.d[1] = WALL + 1024 * 1024;  wa.st[1] = 2048;  wa.mul[1] = 1; wa.add[1] = 0;
  wa.s[2] = Wkv + 1024;  wa.d[2] = WALL + 2048 * 1024;  wa.st[2] = 2048;  wa.mul[2] = 1; wa.add[2] = 0;
  wa.s[3] = Wo;          wa.d[3] = WoT;                 wa.st[3] = 1024;  wa.mul[3] = 1; wa.add[3] = 0;
  wa.s[4] = W1;          wa.d[4] = WALL + 3072 * 1024;  wa.st[4] = 1024;  wa.mul[4] = 2; wa.add[4] = 0;
  wa.s[5] = W2;          wa.d[5] = WALL + 3072 * 1024;  wa.st[5] = 1024;  wa.mul[5] = 2; wa.add[5] = 1;
  wtrans6<<<dim3(32, 32, 6), 256, 0, stream>>>(wa);
  pack_bias<<<16, 256, 0, stream>>>(bq, bkv, b1, b2, ball);
  premask<<<16, 256, 0, stream>>>(msk, MBL);

  // fused QKV + GLU projection: deep-pipelined 640-block dispatch (144KB LDS)
  gemm_qkvglu8<<<640, 512, 3 * 24576 * 2, stream>>>(X, WALL, ball, QKV, X1);
  // V transpose for attention A-operand
  vtrans<<<dim3(64, 32, 2), 256, 0, stream>>>(QKV, VT);
  // flash attention, 2-way K-split -> partials, then merge -> ATT
  attn_kernel<<<dim3(16 * NSPLIT, 16, 2), 256, 0, stream>>>(QKV, VT, MBL, OP, SP);
  attn_merge<<<RH * 8 / 256, 256, 0, stream>>>(OP, SP, ATT);
  // attention out projection: BN=64 tile -> 512 blocks (2/CU)
  gemm_bf16<64><<<dim3(16, 32), 256, 0, stream>>>(ATT, WoT, bo, AO, 1024);
  // out = LayerNorm(h + AO + X1)
  ln_kernel<<<MROWS, 256, 0, stream>>>(h, AO, X1, lng, lnb, out);
}

// Round 13
// 166.447 us; speedup vs baseline: 1.1966x; 1.1966x over previous
//
#include <hip/hip_runtime.h>
#include <hip/hip_bf16.h>

// ---------------------------------------------------------------------------
// Transformer block: LN(h + (softmax(mask(QK^T))V)Wo + sigmoid(hW1)*(hW2))
// B=2 S=2048 D_MODEL=1024 H=16 DH=64.  All heavy math in bf16 MFMA.
// ---------------------------------------------------------------------------

typedef short bf16x8 __attribute__((ext_vector_type(8)));   // 8 bf16 = 4 VGPR
typedef float f32x4  __attribute__((ext_vector_type(4)));
typedef float f32x16 __attribute__((ext_vector_type(16)));
typedef unsigned int u32x4 __attribute__((ext_vector_type(4)));

typedef const __attribute__((address_space(1))) void* gas_cvp;
typedef __attribute__((address_space(3))) void* las_vp;

__device__ __forceinline__ void gload_lds16(const void* g, void* l) {
  __builtin_amdgcn_global_load_lds((gas_cvp)g, (las_vp)l, 16, 0, 0);
}

__device__ __forceinline__ short f2bf(float f) {
  __hip_bfloat16 h = __float2bfloat16(f);
  return *reinterpret_cast<short*>(&h);
}
__device__ __forceinline__ float bf2f(short s) {
  unsigned u = ((unsigned)(unsigned short)s) << 16;
  return __builtin_bit_cast(float, u);
}

#if __has_builtin(__builtin_amdgcn_exp2f)
#define EXP2(x) __builtin_amdgcn_exp2f(x)
#else
#define EXP2(x) exp2f(x)
#endif

constexpr int BATCH = 2;
constexpr int SEQ   = 2048;
constexpr int NH    = 16;
constexpr int MROWS = BATCH * SEQ;   // 4096
constexpr int NSPLIT = 2;            // K-direction split for occupancy
constexpr int KSPL   = SEQ / NSPLIT; // keys per split = 1024
constexpr int RH     = MROWS * NH;   // rowheads = 65536

// ------------------------------- small kernels -----------------------------

__global__ __launch_bounds__(256) void cvt_bf16(const float* __restrict__ src,
                                                short* __restrict__ dst, int n4) {
  int i = blockIdx.x * 256 + threadIdx.x;
  if (i >= n4) return;
  float4 v = reinterpret_cast<const float4*>(src)[i];
  short4 o;
  o.x = f2bf(v.x); o.y = f2bf(v.y); o.z = f2bf(v.z); o.w = f2bf(v.w);
  reinterpret_cast<short4*>(dst)[i] = o;
}

// six 1024x1024 fp32->bf16 transposes in one launch (blockIdx.z selects).
// dst row = n*mul + add  (mul=2 interleaves W1/W2 for the fused-GLU GEMM).
struct WtA {
  const float* s[6];
  short* d[6];
  int st[6];
  int mul[6];
  int add[6];
};
__global__ __launch_bounds__(256) void wtrans6(WtA a) {
  __shared__ float tile[32][33];
  const float* __restrict__ src = a.s[blockIdx.z];
  short* __restrict__ dst = a.d[blockIdx.z];
  const int stride = a.st[blockIdx.z];
  const int mul = a.mul[blockIdx.z], add = a.add[blockIdx.z];
  const int tx = threadIdx.x & 31, ty = threadIdx.x >> 5;   // 32 x 8
  const int n0 = blockIdx.x * 32, k0 = blockIdx.y * 32;
  #pragma unroll
  for (int i = 0; i < 32; i += 8)
    tile[ty + i][tx] = src[(size_t)(k0 + ty + i) * stride + n0 + tx];
  __syncthreads();
  #pragma unroll
  for (int i = 0; i < 32; i += 8)
    dst[(size_t)((n0 + ty + i) * mul + add) * 1024 + k0 + tx] = f2bf(tile[tx][ty + i]);
}

// V-part of QKV [4096][3072] (cols 2048..3071) -> VT [2][1024][2048] bf16
__global__ __launch_bounds__(256) void vtrans(const short* __restrict__ qkv,
                                              short* __restrict__ vt) {
  __shared__ short tile[32][33];
  const int tx = threadIdx.x & 31, ty = threadIdx.x >> 5;
  const int s0 = blockIdx.x * 32, d0 = blockIdx.y * 32, b = blockIdx.z;
  #pragma unroll
  for (int i = 0; i < 32; i += 8)
    tile[ty + i][tx] = qkv[(size_t)(b * SEQ + s0 + ty + i) * 3072 + 2048 + d0 + tx];
  __syncthreads();
  #pragma unroll
  for (int i = 0; i < 32; i += 8)
    vt[(size_t)(b * 1024 + d0 + ty + i) * SEQ + s0 + tx] = tile[tx][ty + i];
}

// ball = [bq | bkv | interleaved {b1,b2}]  (5120 floats)
__global__ void pack_bias(const float* __restrict__ bq, const float* __restrict__ bkv,
                          const float* __restrict__ b1, const float* __restrict__ b2,
                          float* __restrict__ ball) {
  int i = blockIdx.x * 256 + threadIdx.x;
  if (i < 1024) ball[i] = bq[i];
  else if (i < 3072) ball[i] = bkv[i - 1024];
  else if (i < 4096) {
    const int j = i - 3072;
    ball[3072 + 2 * j] = b1[j];
    ball[3072 + 2 * j + 1] = b2[j];
  }
}

__device__ __forceinline__ bool mask_at(const void* mp, int idx, int flag) {
  if (flag == 1) return ((const int*)mp)[idx] != 0;
  if (flag == 2) return ((const float*)mp)[idx] != 0.f;
  return ((const unsigned char*)mp)[idx] != 0;
}

// mask -> additive bias in exp2 domain, with inline dtype detection (mask bool
// may arrive as u8 / i32 / f32). Static-max softmax: fixed -8 shift folded in.
__global__ __launch_bounds__(256) void premask(const void* __restrict__ msk,
                                               float* __restrict__ mbL) {
  __shared__ int si, sf;
  const unsigned* m = (const unsigned*)msk;
  if (threadIdx.x == 0) { si = 1; sf = 1; }
  __syncthreads();
  bool oki = true, okf = true;
  for (int i = threadIdx.x; i < 1024; i += 256) {   // first 4096 bytes, in-bounds always
    unsigned v = m[i];
    oki = oki && (v <= 1u);
    okf = okf && (v == 0u || v == 0x3F800000u);
  }
  if (!oki) si = 0;
  if (!okf) sf = 0;
  __syncthreads();
  const int flag = si ? 1 : (sf ? 2 : 0);
  int i = blockIdx.x * 256 + threadIdx.x;
  if (i < MROWS) mbL[i] = mask_at(msk, i, flag) ? -1.442695e9f : -8.0f;
}

// ------------------------------- GEMM --------------------------------------
// m97 structure, BK=64, conflict-free LDS via pre-swizzled source (G21):
// chunk c of row r stored at position c^(r&7); staging dest stays linear.
// Frag reads are per-lane base + compile-time immediates; 2 lanes/bank (free).

// gemm_bf16<BN>: plain bf16 out, BN = 128 or 64 cols/block.
template <int BN>
__global__ __launch_bounds__(256) void gemm_bf16(const short* __restrict__ A,
                                                 const short* __restrict__ BT,
                                                 const float* __restrict__ bias,
                                                 short* __restrict__ outp, int N) {
  constexpr int NF = BN / 64;
  __shared__ short Alds[128 * 64];
  __shared__ short Blds[BN * 64];
  const int tid = threadIdx.x;
  const int w = tid >> 6, l = tid & 63, lr = l & 15;
  const int wr = w >> 1, wc = w & 1;
  const int bm = blockIdx.y, bn = blockIdx.x;

  f32x4 acc[4][2 * NF] = {};

  const int srow = tid >> 3;
  const int schunk = (tid & 7) ^ (srow & 7);
  const short* Ab = A  + (size_t)(bm * 128 + srow) * 1024 + schunk * 8;
  const short* Bb = BT + (size_t)(bn * BN + srow) * 1024 + schunk * 8;

  const int cg = (l >> 4) ^ (l & 3), fl = (l >> 2) & 1;
  const short* ard[2] = { &Alds[(wr * 64 + lr) * 64 + cg * 8 + fl * 32],
                          &Alds[(wr * 64 + lr) * 64 + cg * 8 + 32 - fl * 32] };
  const short* brd[2] = { &Blds[(wc * (BN / 2) + lr) * 64 + cg * 8 + fl * 32],
                          &Blds[(wc * (BN / 2) + lr) * 64 + cg * 8 + 32 - fl * 32] };

  for (int kt = 0; kt < 16; ++kt) {
    const int kb = kt * 64;
    __syncthreads();
    #pragma unroll
    for (int q = 0; q < 4; ++q)
      gload_lds16(Ab + (size_t)q * 32 * 1024 + kb, &Alds[q * 2048 + tid * 8]);
    #pragma unroll
    for (int q = 0; q < BN / 32; ++q)
      gload_lds16(Bb + (size_t)q * 32 * 1024 + kb, &Blds[q * 2048 + tid * 8]);
    asm volatile("s_waitcnt vmcnt(0)" ::: "memory");
    __syncthreads();

    #pragma unroll
    for (int s = 0; s < 2; ++s) {
      bf16x8 af[4], bfr[2 * NF];
      #pragma unroll
      for (int m = 0; m < 4; ++m)
        af[m] = *reinterpret_cast<const bf16x8*>(ard[s] + m * 16 * 64);
      #pragma unroll
      for (int n = 0; n < 2 * NF; ++n)
        bfr[n] = *reinterpret_cast<const bf16x8*>(brd[s] + n * 16 * 64);
      #pragma unroll
      for (int m = 0; m < 4; ++m)
        #pragma unroll
        for (int n = 0; n < 2 * NF; ++n)
          acc[m][n] = __builtin_amdgcn_mfma_f32_16x16x32_bf16(af[m], bfr[n], acc[m][n], 0, 0, 0);
    }
  }

  const int g = l >> 4;
  #pragma unroll
  for (int m = 0; m < 4; ++m) {
    const int row = bm * 128 + wr * 64 + m * 16 + g * 4;
    #pragma unroll
    for (int n = 0; n < 2 * NF; ++n) {
      const int col = bn * BN + wc * (BN / 2) + n * 16 + lr;
      const float bv = bias[col];
      #pragma unroll
      for (int r = 0; r < 4; ++r)
        outp[(size_t)(row + r) * N + col] = f2bf(acc[m][n][r] + bv);
    }
  }
}

// Fused QKV + GLU GEMM (R11 structure), 1D grid 1280 with XCD-chunked swizzle:
// each XCD owns a contiguous 4-bm chunk (1MB of A, L2-resident) sweeping all
// 40 bn.  bn<24 -> QKV bf16 out; bn>=24 -> GLU parity trick -> X1.
__global__ __launch_bounds__(256) void gemm_qkvglu(const short* __restrict__ A,
                                                   const short* __restrict__ BT,
                                                   const float* __restrict__ bias,
                                                   short* __restrict__ qkv,
                                                   short* __restrict__ x1) {
  __shared__ short Alds[128 * 64];
  __shared__ short Blds[128 * 64];
  const int tid = threadIdx.x;
  const int w = tid >> 6, l = tid & 63, lr = l & 15;
  const int wr = w >> 1, wc = w & 1;
  // XCD-chunked decode: xcd = idx&7 gets bm in {4*xcd .. 4*xcd+3}, all bn.
  const int idx = blockIdx.x;
  const int local = idx >> 3;
  const int bm = (idx & 7) * 4 + (local & 3);
  const int bn = local >> 2;

  f32x4 acc[4][4] = {};

  const int srow = tid >> 3;
  const int schunk = (tid & 7) ^ (srow & 7);
  const short* Ab = A  + (size_t)(bm * 128 + srow) * 1024 + schunk * 8;
  const short* Bb = BT + (size_t)(bn * 128 + srow) * 1024 + schunk * 8;

  const int cg = (l >> 4) ^ (l & 3), fl = (l >> 2) & 1;
  const short* ard[2] = { &Alds[(wr * 64 + lr) * 64 + cg * 8 + fl * 32],
                          &Alds[(wr * 64 + lr) * 64 + cg * 8 + 32 - fl * 32] };
  const short* brd[2] = { &Blds[(wc * 64 + lr) * 64 + cg * 8 + fl * 32],
                          &Blds[(wc * 64 + lr) * 64 + cg * 8 + 32 - fl * 32] };

  for (int kt = 0; kt < 16; ++kt) {
    const int kb = kt * 64;
    __syncthreads();
    #pragma unroll
    for (int q = 0; q < 4; ++q) {
      gload_lds16(Ab + (size_t)q * 32 * 1024 + kb, &Alds[q * 2048 + tid * 8]);
      gload_lds16(Bb + (size_t)q * 32 * 1024 + kb, &Blds[q * 2048 + tid * 8]);
    }
    asm volatile("s_waitcnt vmcnt(0)" ::: "memory");
    __syncthreads();

    #pragma unroll
    for (int s = 0; s < 2; ++s) {
      bf16x8 af[4], bfr[4];
      #pragma unroll
      for (int m = 0; m < 4; ++m)
        af[m] = *reinterpret_cast<const bf16x8*>(ard[s] + m * 16 * 64);
      #pragma unroll
      for (int n = 0; n < 4; ++n)
        bfr[n] = *reinterpret_cast<const bf16x8*>(brd[s] + n * 16 * 64);
      #pragma unroll
      for (int m = 0; m < 4; ++m)
        #pragma unroll
        for (int n = 0; n < 4; ++n)
          acc[m][n] = __builtin_amdgcn_mfma_f32_16x16x32_bf16(af[m], bfr[n], acc[m][n], 0, 0, 0);
    }
  }

  const int g = l >> 4;
  const bool isGlu = (bn >= 24);
  #pragma unroll
  for (int m = 0; m < 4; ++m) {
    const int row = bm * 128 + wr * 64 + m * 16 + g * 4;
    #pragma unroll
    for (int n = 0; n < 4; ++n) {
      const int col = bn * 128 + wc * 64 + n * 16 + lr;
      const float bv = bias[col];
      #pragma unroll
      for (int r = 0; r < 4; ++r) {
        const float v = acc[m][n][r] + bv;
        if (!isGlu) {
          qkv[(size_t)(row + r) * 3072 + col] = f2bf(v);
        } else {
          // interleaved cols: even lane = x1, odd neighbor = x2
          const float vp = __shfl_xor(v, 1);
          if (!(lr & 1)) {
            const int col2 = col - 3072;
            x1[(size_t)(row + r) * 1024 + (col2 >> 1)] = f2bf(vp / (1.f + __expf(-v)));
          }
        }
      }
    }
  }
}

// ------------------------------- attention v8 -------------------------------
// Swapped-operand 32x32x16, 2-way K-split, KB=64, double-buffer granule-padded
// LDS with reg staging and ONE barrier per tile.  1D grid with XCD-chunked
// swizzle: 32 consecutive blocks (one (b,h): K/V = 512KB) land on one XCD ->
// K/V L2-resident.  Static-max softmax, permlane32_swap P redistribution.
constexpr int KB = 64;               // keys per tile
constexpr int KSLOT = 8 * 66;        // K granule-major [8][66] 16B slots
constexpr int VSLOT = 8 * 66;        // V^T granule-major [8][66]

__global__ __launch_bounds__(256) void attn_kernel(const short* __restrict__ qkv,
                                                   const short* __restrict__ vt,
                                                   const float* __restrict__ mbL,
                                                   short* __restrict__ opart,
                                                   float* __restrict__ spart) {
  __shared__ short Kl[2][KSLOT * 8];   // 2 x 8.25 KB
  __shared__ short Vl[2][VSLOT * 8];   // 2 x 8.25 KB
  __shared__ float mb[KSPL];           // 4 KB mask bias (log2 domain, -8 shift)

  const int tid = threadIdx.x;
  const int w = tid >> 6, lane = tid & 63, ql = lane & 31, hi = lane >> 5;
  // XCD-chunked decode (1024 blocks, 1024%8==0): xcd gets 128 consecutive ids
  // = 4 (b,h) pairs x 32 (qb,sp) blocks.
  const int idx = blockIdx.x;
  const int swz = (idx & 7) * 128 + (idx >> 3);
  const int sp = swz & 1, qb = (swz >> 1) & 15;
  const int h = (swz >> 5) & 15, b = swz >> 9;
  const int qrow = qb * 128 + w * 32 + ql;
  const int kofs = sp * KSPL;

  // ---- hoist Q fragments (B-operand: lane q holds Q[q][c*16 + hi*8 + j]) ----
  bf16x8 qf[4];
  {
    const short* qp = qkv + (size_t)(b * SEQ + qrow) * 3072 + h * 64;
    #pragma unroll
    for (int c = 0; c < 4; ++c)
      qf[c] = *reinterpret_cast<const bf16x8*>(qp + c * 16 + hi * 8);
  }

  // ---- staging maps (per-thread constants) ----
  const short* gkbase = qkv + (size_t)(b * SEQ + kofs) * 3072 + 1024 + h * 64
                        + (size_t)(tid >> 3) * 3072 + (tid & 7) * 8;
  const short* gvbase = vt + ((size_t)(b * 1024 + h * 64) + (tid >> 3)) * SEQ + kofs
                        + (tid & 7) * 8;
  short* kwr = &Kl[0][((tid & 7) * 66 + (tid >> 3)) * 8];
  short* vwr = &Vl[0][((tid & 7) * 66 + (tid >> 3)) * 8];

  u32x4 kreg0, kreg1, vreg0, vreg1;
  auto loadTile = [&](int kt) {
    const short* gk = gkbase + (size_t)kt * KB * 3072;
    kreg0 = *reinterpret_cast<const u32x4*>(gk);
    kreg1 = *reinterpret_cast<const u32x4*>(gk + 32 * 3072);
    const short* gv = gvbase + kt * KB;
    vreg0 = *reinterpret_cast<const u32x4*>(gv);
    vreg1 = *reinterpret_cast<const u32x4*>(gv + 32 * SEQ);
  };
  auto writeTile = [&](int buf) {
    short* kd = kwr + buf * KSLOT * 8;
    *reinterpret_cast<u32x4*>(kd)          = kreg0;   // compiler waits vmcnt here
    *reinterpret_cast<u32x4*>(kd + 32 * 8) = kreg1;
    short* vd = vwr + buf * VSLOT * 8;
    *reinterpret_cast<u32x4*>(vd)          = vreg0;
    *reinterpret_cast<u32x4*>(vd + 32 * 8) = vreg1;
  };

  float s_run = 0.f;
  f32x16 oacc0 = {}, oacc1 = {};

  // ---- prologue: mask bias (4KB, all waves) + tile 0 ----
  gload_lds16(mbL + b * SEQ + kofs + tid * 4, &mb[tid * 4]);
  loadTile(0);
  writeTile(0);
  __syncthreads();

  // per-lane LDS read bases (constant; reads use +imm offsets)
  const short* krd = &Kl[0][(hi * 66 + ql) * 8];
  const short* vrd = &Vl[0][(hi * 66 + ql) * 8];

  constexpr int NT = KSPL / KB;   // 16
  for (int kt = 0; kt < NT; ++kt) {
    const int cur = kt & 1;
    if (kt + 1 < NT) loadTile(kt + 1);   // HBM latency hides under compute(t)
    const short* Kb = krd + cur * KSLOT * 8;
    const short* Vb = vrd + cur * VSLOT * 8;

    #pragma unroll
    for (int t2 = 0; t2 < 2; ++t2) {
      // QK^T: S[k][q]
      f32x16 sc = {};
      __builtin_amdgcn_s_setprio(1);
      #pragma unroll
      for (int c = 0; c < 4; ++c) {
        bf16x8 kf = *reinterpret_cast<const bf16x8*>(Kb + (c * 132 + t2 * 32) * 8);
        sc = __builtin_amdgcn_mfma_f32_32x32x16_bf16(kf, qf[c], sc, 0, 0, 0);
      }
      __builtin_amdgcn_s_setprio(0);
      // p = exp2(score*scale*log2e + bias)   (bias = mask? -1.4e9 : -8)
      float p[16];
      #pragma unroll
      for (int u = 0; u < 4; ++u) {
        float4 m4 = *reinterpret_cast<const float4*>(&mb[kt * KB + t2 * 32 + u * 8 + hi * 4]);
        p[4 * u + 0] = EXP2(fmaf(sc[4 * u + 0], 0.18033688f, m4.x));   // 0.125*log2e
        p[4 * u + 1] = EXP2(fmaf(sc[4 * u + 1], 0.18033688f, m4.y));
        p[4 * u + 2] = EXP2(fmaf(sc[4 * u + 2], 0.18033688f, m4.z));
        p[4 * u + 3] = EXP2(fmaf(sc[4 * u + 3], 0.18033688f, m4.w));
      }
      // partial-sum tree (cross-lane deferred to epilogue)
      {
        float a0 = (p[0] + p[1]) + (p[2] + p[3]);
        float a1 = (p[4] + p[5]) + (p[6] + p[7]);
        float a2 = (p[8] + p[9]) + (p[10] + p[11]);
        float a3 = (p[12] + p[13]) + (p[14] + p[15]);
        s_run += (a0 + a1) + (a2 + a3);
      }
      // pack P -> bf16 pairs; permlane32_swap redistributes across half-waves
      unsigned P[8];
      #pragma unroll
      for (int j = 0; j < 8; ++j)
        asm("v_cvt_pk_bf16_f32 %0, %1, %2" : "=v"(P[j]) : "v"(p[2 * j]), "v"(p[2 * j + 1]));
      asm("v_permlane32_swap_b32 %0, %1" : "+v"(P[0]), "+v"(P[2]));
      asm("v_permlane32_swap_b32 %0, %1" : "+v"(P[1]), "+v"(P[3]));
      asm("v_permlane32_swap_b32 %0, %1" : "+v"(P[4]), "+v"(P[6]));
      asm("v_permlane32_swap_b32 %0, %1" : "+v"(P[5]), "+v"(P[7]));
      u32x4 c0 = { P[0], P[1], P[2], P[3] };
      u32x4 c1 = { P[4], P[5], P[6], P[7] };
      bf16x8 pf[2] = { __builtin_bit_cast(bf16x8, c0), __builtin_bit_cast(bf16x8, c1) };

      // PV: O^T[d][q] += V^T[d][k] P[k][q]
      __builtin_amdgcn_s_setprio(1);
      #pragma unroll
      for (int ch = 0; ch < 2; ++ch) {
        const int gb = (t2 * 4 + ch * 2) * 66;
        bf16x8 v0 = *reinterpret_cast<const bf16x8*>(Vb + gb * 8);
        bf16x8 v1 = *reinterpret_cast<const bf16x8*>(Vb + (gb + 32) * 8);
        oacc0 = __builtin_amdgcn_mfma_f32_32x32x16_bf16(v0, pf[ch], oacc0, 0, 0, 0);
        oacc1 = __builtin_amdgcn_mfma_f32_32x32x16_bf16(v1, pf[ch], oacc1, 0, 0, 0);
      }
      __builtin_amdgcn_s_setprio(0);
    }

    if (kt + 1 < NT) {
      writeTile(cur ^ 1);   // cur^1 readers finished at end of tile kt-1
      __syncthreads();      // writes visible before tile kt+1 reads
    }
  }

  // ---- epilogue: finish sum across half-waves, store unnormalized O + s ----
  const float sT = s_run + __shfl_xor(s_run, 32);
  const size_t obase = (size_t)sp * RH * 64 + (size_t)(b * SEQ + qrow) * 1024 + h * 64;
  #pragma unroll
  for (int dt = 0; dt < 2; ++dt) {
    #pragma unroll
    for (int u = 0; u < 4; ++u) {
      short4 st;
      const f32x16& oa = dt ? oacc1 : oacc0;
      st.x = f2bf(oa[4 * u + 0]);
      st.y = f2bf(oa[4 * u + 1]);
      st.z = f2bf(oa[4 * u + 2]);
      st.w = f2bf(oa[4 * u + 3]);
      *reinterpret_cast<short4*>(&opart[obase + dt * 32 + u * 8 + hi * 4]) = st;
    }
  }
  if (hi == 0)
    spart[sp * RH + (b * SEQ + qrow) * NH + h] = sT;
}

// merge K-splits: att = sum(O_s) / sum(s_s)   (same fixed shift cancels)
__global__ __launch_bounds__(256) void attn_merge(const short* __restrict__ opart,
                                                  const float* __restrict__ spart,
                                                  short* __restrict__ att) {
  const int idx = blockIdx.x * 256 + threadIdx.x;   // RH*8 = 524288
  const int rh = idx >> 3;
  const size_t base = (size_t)rh * 64 + (idx & 7) * 8;
  float acc[8] = {};
  float ss = 0.f;
  #pragma unroll
  for (int s = 0; s < NSPLIT; ++s) {
    bf16x8 o = *reinterpret_cast<const bf16x8*>(&opart[(size_t)s * RH * 64 + base]);
    #pragma unroll
    for (int j = 0; j < 8; ++j) acc[j] += bf2f(o[j]);
    ss += spart[s * RH + rh];
  }
  const float inv = 1.f / ss;
  bf16x8 r;
  #pragma unroll
  for (int j = 0; j < 8; ++j) r[j] = f2bf(acc[j] * inv);
  *reinterpret_cast<bf16x8*>(&att[base]) = r;
}

// -------------------------- residual + LayerNorm ----------------------------
// Vectorized: thread t handles cols 4t..4t+3 (float4 / short4 loads).
__global__ __launch_bounds__(256) void ln_kernel(const float* __restrict__ h,
                                                 const short* __restrict__ ao,
                                                 const short* __restrict__ gl,
                                                 const float* __restrict__ gamma,
                                                 const float* __restrict__ beta,
                                                 float* __restrict__ out) {
  const int row = blockIdx.x;
  const size_t base = (size_t)row * 1024;
  const int t = threadIdx.x;
  __shared__ float red[4];
  float4 x = reinterpret_cast<const float4*>(h + base)[t];
  const short4 a4 = reinterpret_cast<const short4*>(ao + base)[t];
  const short4 g4 = reinterpret_cast<const short4*>(gl + base)[t];
  x.x += bf2f(a4.x) + bf2f(g4.x);
  x.y += bf2f(a4.y) + bf2f(g4.y);
  x.z += bf2f(a4.z) + bf2f(g4.z);
  x.w += bf2f(a4.w) + bf2f(g4.w);
  float s = (x.x + x.y) + (x.z + x.w);
  #pragma unroll
  for (int d = 1; d < 64; d <<= 1) s += __shfl_xor(s, d);
  if ((t & 63) == 0) red[t >> 6] = s;
  __syncthreads();
  const float mu = (red[0] + red[1] + red[2] + red[3]) * (1.f / 1024.f);
  __syncthreads();
  const float dx0 = x.x - mu, dx1 = x.y - mu, dx2 = x.z - mu, dx3 = x.w - mu;
  float vs = (dx0 * dx0 + dx1 * dx1) + (dx2 * dx2 + dx3 * dx3);
  #pragma unroll
  for (int d = 1; d < 64; d <<= 1) vs += __shfl_xor(vs, d);
  if ((t & 63) == 0) red[t >> 6] = vs;
  __syncthreads();
  const float var = (red[0] + red[1] + red[2] + red[3]) * (1.f / 1024.f);
  const float rs = rsqrtf(var + 1e-6f);
  const float4 gm = reinterpret_cast<const float4*>(gamma)[t];
  const float4 bt = reinterpret_cast<const float4*>(beta)[t];
  float4 o;
  o.x = dx0 * rs * gm.x + bt.x;
  o.y = dx1 * rs * gm.y + bt.y;
  o.z = dx2 * rs * gm.z + bt.z;
  o.w = dx3 * rs * gm.w + bt.w;
  reinterpret_cast<float4*>(out + base)[t] = o;
}

// ------------------------------- launcher ----------------------------------

extern "C" void kernel_launch(void* const* d_in, const int* in_sizes, int n_in,
                              void* d_out, int out_size, void* d_ws, size_t ws_size,
                              hipStream_t stream) {
  const float* h   = (const float*)d_in[0];
  const void*  msk = d_in[1];
  const float* Wq  = (const float*)d_in[2];
  const float* bq  = (const float*)d_in[3];
  const float* Wkv = (const float*)d_in[4];
  const float* bkv = (const float*)d_in[5];
  const float* Wo  = (const float*)d_in[6];
  const float* bo  = (const float*)d_in[7];
  const float* W1  = (const float*)d_in[8];
  const float* b1  = (const float*)d_in[9];
  const float* W2  = (const float*)d_in[10];
  const float* b2  = (const float*)d_in[11];
  const float* lng = (const float*)d_in[12];
  const float* lnb = (const float*)d_in[13];
  float* out = (float*)d_out;

  char* ws = (char*)d_ws;
  size_t off = 0;
  auto alloc = [&](size_t bytes) {
    char* p = ws + off;
    off += (bytes + 255) & ~(size_t)255;
    return p;
  };
  short* X     = (short*)alloc((size_t)MROWS * 1024 * 2);   // h in bf16
  short* WALL  = (short*)alloc((size_t)5120 * 1024 * 2);    // [Wq|Wkv|W1/W2 ilv]^T
  short* WoT   = (short*)alloc((size_t)1024 * 1024 * 2);
  float* ball  = (float*)alloc(5120 * 4);
  float* MBL   = (float*)alloc((size_t)MROWS * 4);          // mask bias (log2 dom)
  short* QKV   = (short*)alloc((size_t)MROWS * 3072 * 2);
  short* VT    = (short*)alloc((size_t)BATCH * 1024 * SEQ * 2);  // V transposed
  short* ATT   = (short*)alloc((size_t)MROWS * 1024 * 2);
  short* X1    = (short*)alloc((size_t)MROWS * 1024 * 2);   // GLU result bf16
  short* AO    = (short*)alloc((size_t)MROWS * 1024 * 2);   // attention proj bf16
  short* OP    = (short*)alloc((size_t)NSPLIT * RH * 64 * 2);  // partial O (unnorm)
  float* SP    = (float*)alloc((size_t)NSPLIT * RH * 4);       // partial sums
  if (off > ws_size) return;  // workspace too small: bail visibly

  cvt_bf16<<<4096, 256, 0, stream>>>(h, X, MROWS * 1024 / 4);
  WtA wa;
  wa.s[0] = Wq;          wa.d[0] = WALL;                wa.st[0] = 1024;  wa.mul[0] = 1; wa.add[0] = 0;
  wa.s[1] = Wkv;         wa.d[1] = WALL + 1024 * 1024;  wa.st[1] = 2048;  wa.mul[1] = 1; wa.add[1] = 0;
  wa.s[2] = Wkv + 1024;  wa.d[2] = WALL + 2048 * 1024;  wa.st[2] = 2048;  wa.mul[2] = 1; wa.add[2] = 0;
  wa.s[3] = Wo;          wa.d[3] = WoT;                 wa.st[3] = 1024;  wa.mul[3] = 1; wa.add[3] = 0;
  wa.s[4] = W1;          wa.d[4] = WALL + 3072 * 1024;  wa.st[4] = 1024;  wa.mul[4] = 2; wa.add[4] = 0;
  wa.s[5] = W2;          wa.d[5] = WALL + 3072 * 1024;  wa.st[5] = 1024;  wa.mul[5] = 2; wa.add[5] = 1;
  wtrans6<<<dim3(32, 32, 6), 256, 0, stream>>>(wa);
  pack_bias<<<16, 256, 0, stream>>>(bq, bkv, b1, b2, ball);
  premask<<<16, 256, 0, stream>>>(msk, MBL);

  // fused QKV + GLU projection (1280 blocks, XCD-chunked)
  gemm_qkvglu<<<1280, 256, 0, stream>>>(X, WALL, ball, QKV, X1);
  // V transpose for attention A-operand
  vtrans<<<dim3(64, 32, 2), 256, 0, stream>>>(QKV, VT);
  // flash attention, 2-way K-split -> partials, then merge -> ATT
  attn_kernel<<<1024, 256, 0, stream>>>(QKV, VT, MBL, OP, SP);
  attn_merge<<<RH * 8 / 256, 256, 0, stream>>>(OP, SP, ATT);
  // attention out projection: BN=64 tile -> 512 blocks (2/CU)
  gemm_bf16<64><<<dim3(16, 32), 256, 0, stream>>>(ATT, WoT, bo, AO, 1024);
  // out = LayerNorm(h + AO + X1)
  ln_kernel<<<MROWS, 256, 0, stream>>>(h, AO, X1, lng, lnb, out);
}

// Round 14
// 157.779 us; speedup vs baseline: 1.2623x; 1.0549x over previous
//
#include <hip/hip_runtime.h>
#include <hip/hip_bf16.h>

// ---------------------------------------------------------------------------
// Transformer block: LN(h + (softmax(mask(QK^T))V)Wo + sigmoid(hW1)*(hW2))
// B=2 S=2048 D_MODEL=1024 H=16 DH=64.  All heavy math in bf16 MFMA.
// ---------------------------------------------------------------------------

typedef short bf16x8 __attribute__((ext_vector_type(8)));   // 8 bf16 = 4 VGPR
typedef float f32x4  __attribute__((ext_vector_type(4)));
typedef float f32x16 __attribute__((ext_vector_type(16)));
typedef unsigned int u32x4 __attribute__((ext_vector_type(4)));

typedef const __attribute__((address_space(1))) void* gas_cvp;
typedef __attribute__((address_space(3))) void* las_vp;

__device__ __forceinline__ void gload_lds16(const void* g, void* l) {
  __builtin_amdgcn_global_load_lds((gas_cvp)g, (las_vp)l, 16, 0, 0);
}

__device__ __forceinline__ short f2bf(float f) {
  __hip_bfloat16 h = __float2bfloat16(f);
  return *reinterpret_cast<short*>(&h);
}
__device__ __forceinline__ float bf2f(short s) {
  unsigned u = ((unsigned)(unsigned short)s) << 16;
  return __builtin_bit_cast(float, u);
}

#if __has_builtin(__builtin_amdgcn_exp2f)
#define EXP2(x) __builtin_amdgcn_exp2f(x)
#else
#define EXP2(x) exp2f(x)
#endif

constexpr int BATCH = 2;
constexpr int SEQ   = 2048;
constexpr int NH    = 16;
constexpr int MROWS = BATCH * SEQ;   // 4096

// ------------------------------- small kernels -----------------------------

__global__ __launch_bounds__(256) void cvt_bf16(const float* __restrict__ src,
                                                short* __restrict__ dst, int n4) {
  int i = blockIdx.x * 256 + threadIdx.x;
  if (i >= n4) return;
  float4 v = reinterpret_cast<const float4*>(src)[i];
  short4 o;
  o.x = f2bf(v.x); o.y = f2bf(v.y); o.z = f2bf(v.z); o.w = f2bf(v.w);
  reinterpret_cast<short4*>(dst)[i] = o;
}

// six 1024x1024 fp32->bf16 transposes in one launch (blockIdx.z selects).
// dst row = n*mul + add  (mul=2 interleaves W1/W2 for the fused-GLU GEMM).
struct WtA {
  const float* s[6];
  short* d[6];
  int st[6];
  int mul[6];
  int add[6];
};
__global__ __launch_bounds__(256) void wtrans6(WtA a) {
  __shared__ float tile[32][33];
  const float* __restrict__ src = a.s[blockIdx.z];
  short* __restrict__ dst = a.d[blockIdx.z];
  const int stride = a.st[blockIdx.z];
  const int mul = a.mul[blockIdx.z], add = a.add[blockIdx.z];
  const int tx = threadIdx.x & 31, ty = threadIdx.x >> 5;   // 32 x 8
  const int n0 = blockIdx.x * 32, k0 = blockIdx.y * 32;
  #pragma unroll
  for (int i = 0; i < 32; i += 8)
    tile[ty + i][tx] = src[(size_t)(k0 + ty + i) * stride + n0 + tx];
  __syncthreads();
  #pragma unroll
  for (int i = 0; i < 32; i += 8)
    dst[(size_t)((n0 + ty + i) * mul + add) * 1024 + k0 + tx] = f2bf(tile[tx][ty + i]);
}

// ball = [bq | bkv | interleaved {b1,b2}]  (5120 floats)
__global__ void pack_bias(const float* __restrict__ bq, const float* __restrict__ bkv,
                          const float* __restrict__ b1, const float* __restrict__ b2,
                          float* __restrict__ ball) {
  int i = blockIdx.x * 256 + threadIdx.x;
  if (i < 1024) ball[i] = bq[i];
  else if (i < 3072) ball[i] = bkv[i - 1024];
  else if (i < 4096) {
    const int j = i - 3072;
    ball[3072 + 2 * j] = b1[j];
    ball[3072 + 2 * j + 1] = b2[j];
  }
}

__device__ __forceinline__ bool mask_at(const void* mp, int idx, int flag) {
  if (flag == 1) return ((const int*)mp)[idx] != 0;
  if (flag == 2) return ((const float*)mp)[idx] != 0.f;
  return ((const unsigned char*)mp)[idx] != 0;
}

// mask -> additive bias in exp2 domain, with inline dtype detection (mask bool
// may arrive as u8 / i32 / f32). Static-max softmax: fixed -8 shift folded in.
__global__ __launch_bounds__(256) void premask(const void* __restrict__ msk,
                                               float* __restrict__ mbL) {
  __shared__ int si, sf;
  const unsigned* m = (const unsigned*)msk;
  if (threadIdx.x == 0) { si = 1; sf = 1; }
  __syncthreads();
  bool oki = true, okf = true;
  for (int i = threadIdx.x; i < 1024; i += 256) {   // first 4096 bytes, in-bounds always
    unsigned v = m[i];
    oki = oki && (v <= 1u);
    okf = okf && (v == 0u || v == 0x3F800000u);
  }
  if (!oki) si = 0;
  if (!okf) sf = 0;
  __syncthreads();
  const int flag = si ? 1 : (sf ? 2 : 0);
  int i = blockIdx.x * 256 + threadIdx.x;
  if (i < MROWS) mbL[i] = mask_at(msk, i, flag) ? -1.442695e9f : -8.0f;
}

// ------------------------------- GEMM --------------------------------------
// m97 structure, BK=64, conflict-free LDS via pre-swizzled source (G21):
// chunk c of row r stored at position c^(r&7); staging dest stays linear.
// Frag reads are per-lane base + compile-time immediates; 2 lanes/bank (free).

// gemm_bf16<BN>: plain bf16 out, BN = 128 or 64 cols/block.
template <int BN>
__global__ __launch_bounds__(256) void gemm_bf16(const short* __restrict__ A,
                                                 const short* __restrict__ BT,
                                                 const float* __restrict__ bias,
                                                 short* __restrict__ outp, int N) {
  constexpr int NF = BN / 64;
  __shared__ short Alds[128 * 64];
  __shared__ short Blds[BN * 64];
  const int tid = threadIdx.x;
  const int w = tid >> 6, l = tid & 63, lr = l & 15;
  const int wr = w >> 1, wc = w & 1;
  const int bm = blockIdx.y, bn = blockIdx.x;

  f32x4 acc[4][2 * NF] = {};

  const int srow = tid >> 3;
  const int schunk = (tid & 7) ^ (srow & 7);
  const short* Ab = A  + (size_t)(bm * 128 + srow) * 1024 + schunk * 8;
  const short* Bb = BT + (size_t)(bn * BN + srow) * 1024 + schunk * 8;

  const int cg = (l >> 4) ^ (l & 3), fl = (l >> 2) & 1;
  const short* ard[2] = { &Alds[(wr * 64 + lr) * 64 + cg * 8 + fl * 32],
                          &Alds[(wr * 64 + lr) * 64 + cg * 8 + 32 - fl * 32] };
  const short* brd[2] = { &Blds[(wc * (BN / 2) + lr) * 64 + cg * 8 + fl * 32],
                          &Blds[(wc * (BN / 2) + lr) * 64 + cg * 8 + 32 - fl * 32] };

  for (int kt = 0; kt < 16; ++kt) {
    const int kb = kt * 64;
    __syncthreads();
    #pragma unroll
    for (int q = 0; q < 4; ++q)
      gload_lds16(Ab + (size_t)q * 32 * 1024 + kb, &Alds[q * 2048 + tid * 8]);
    #pragma unroll
    for (int q = 0; q < BN / 32; ++q)
      gload_lds16(Bb + (size_t)q * 32 * 1024 + kb, &Blds[q * 2048 + tid * 8]);
    asm volatile("s_waitcnt vmcnt(0)" ::: "memory");
    __syncthreads();

    #pragma unroll
    for (int s = 0; s < 2; ++s) {
      bf16x8 af[4], bfr[2 * NF];
      #pragma unroll
      for (int m = 0; m < 4; ++m)
        af[m] = *reinterpret_cast<const bf16x8*>(ard[s] + m * 16 * 64);
      #pragma unroll
      for (int n = 0; n < 2 * NF; ++n)
        bfr[n] = *reinterpret_cast<const bf16x8*>(brd[s] + n * 16 * 64);
      #pragma unroll
      for (int m = 0; m < 4; ++m)
        #pragma unroll
        for (int n = 0; n < 2 * NF; ++n)
          acc[m][n] = __builtin_amdgcn_mfma_f32_16x16x32_bf16(af[m], bfr[n], acc[m][n], 0, 0, 0);
    }
  }

  const int g = l >> 4;
  #pragma unroll
  for (int m = 0; m < 4; ++m) {
    const int row = bm * 128 + wr * 64 + m * 16 + g * 4;
    #pragma unroll
    for (int n = 0; n < 2 * NF; ++n) {
      const int col = bn * BN + wc * (BN / 2) + n * 16 + lr;
      const float bv = bias[col];
      #pragma unroll
      for (int r = 0; r < 4; ++r)
        outp[(size_t)(row + r) * N + col] = f2bf(acc[m][n][r] + bv);
    }
  }
}

// Fused QKV + GLU GEMM (2-phase plateau structure), 1280 blocks XCD-chunked.
// Epilogue routes by bn: Q/K (col<2048) -> qkv row-major; V (bn 16..23) ->
// VT DIRECTLY TRANSPOSED (short4 of 4 consecutive seq positions per store —
// replaces the vtrans kernel); bn>=24 -> GLU parity trick -> X1.
__global__ __launch_bounds__(256) void gemm_qkvglu(const short* __restrict__ A,
                                                   const short* __restrict__ BT,
                                                   const float* __restrict__ bias,
                                                   short* __restrict__ qkv,
                                                   short* __restrict__ vt,
                                                   short* __restrict__ x1) {
  __shared__ short Alds[128 * 64];
  __shared__ short Blds[128 * 64];
  const int tid = threadIdx.x;
  const int w = tid >> 6, l = tid & 63, lr = l & 15;
  const int wr = w >> 1, wc = w & 1;
  // XCD-chunked decode: xcd = idx&7 gets bm in {4*xcd .. 4*xcd+3}, all bn.
  const int idx = blockIdx.x;
  const int local = idx >> 3;
  const int bm = (idx & 7) * 4 + (local & 3);
  const int bn = local >> 2;

  f32x4 acc[4][4] = {};

  const int srow = tid >> 3;
  const int schunk = (tid & 7) ^ (srow & 7);
  const short* Ab = A  + (size_t)(bm * 128 + srow) * 1024 + schunk * 8;
  const short* Bb = BT + (size_t)(bn * 128 + srow) * 1024 + schunk * 8;

  const int cg = (l >> 4) ^ (l & 3), fl = (l >> 2) & 1;
  const short* ard[2] = { &Alds[(wr * 64 + lr) * 64 + cg * 8 + fl * 32],
                          &Alds[(wr * 64 + lr) * 64 + cg * 8 + 32 - fl * 32] };
  const short* brd[2] = { &Blds[(wc * 64 + lr) * 64 + cg * 8 + fl * 32],
                          &Blds[(wc * 64 + lr) * 64 + cg * 8 + 32 - fl * 32] };

  for (int kt = 0; kt < 16; ++kt) {
    const int kb = kt * 64;
    __syncthreads();
    #pragma unroll
    for (int q = 0; q < 4; ++q) {
      gload_lds16(Ab + (size_t)q * 32 * 1024 + kb, &Alds[q * 2048 + tid * 8]);
      gload_lds16(Bb + (size_t)q * 32 * 1024 + kb, &Blds[q * 2048 + tid * 8]);
    }
    asm volatile("s_waitcnt vmcnt(0)" ::: "memory");
    __syncthreads();

    #pragma unroll
    for (int s = 0; s < 2; ++s) {
      bf16x8 af[4], bfr[4];
      #pragma unroll
      for (int m = 0; m < 4; ++m)
        af[m] = *reinterpret_cast<const bf16x8*>(ard[s] + m * 16 * 64);
      #pragma unroll
      for (int n = 0; n < 4; ++n)
        bfr[n] = *reinterpret_cast<const bf16x8*>(brd[s] + n * 16 * 64);
      #pragma unroll
      for (int m = 0; m < 4; ++m)
        #pragma unroll
        for (int n = 0; n < 4; ++n)
          acc[m][n] = __builtin_amdgcn_mfma_f32_16x16x32_bf16(af[m], bfr[n], acc[m][n], 0, 0, 0);
    }
  }

  const int g = l >> 4;
  #pragma unroll
  for (int m = 0; m < 4; ++m) {
    const int row = bm * 128 + wr * 64 + m * 16 + g * 4;
    #pragma unroll
    for (int n = 0; n < 4; ++n) {
      const int col = bn * 128 + wc * 64 + n * 16 + lr;
      const float bv = bias[col];
      float v[4];
      #pragma unroll
      for (int r = 0; r < 4; ++r) v[r] = acc[m][n][r] + bv;
      if (bn >= 24) {
        // GLU: interleaved cols, even lane = x1, odd neighbor = x2
        #pragma unroll
        for (int r = 0; r < 4; ++r) {
          const float vp = __shfl_xor(v[r], 1);
          if (!(lr & 1))
            x1[(size_t)(row + r) * 1024 + ((col - 3072) >> 1)] =
                f2bf(vp / (1.f + __expf(-v[r])));
        }
      } else if (col < 2048) {
        // Q, K: row-major into QKV
        #pragma unroll
        for (int r = 0; r < 4; ++r)
          qkv[(size_t)(row + r) * 3072 + col] = f2bf(v[r]);
      } else {
        // V: transposed into VT [2][1024][2048]; 4 consecutive seq = short4
        short4 st;
        st.x = f2bf(v[0]); st.y = f2bf(v[1]); st.z = f2bf(v[2]); st.w = f2bf(v[3]);
        *reinterpret_cast<short4*>(
            &vt[((size_t)((row >> 11) * 1024 + (col - 2048))) * SEQ + (row & 2047)]) = st;
      }
    }
  }
}

// ------------------------------- attention v9 -------------------------------
// Swapped-operand 32x32x16, NO K-split (full 2048 keys per block -> direct
// normalized output, merge kernel deleted).  512 blocks = 2/CU (residency is
// reg-capped at ~8 waves/CU anyway).  KB=64 double-buffer granule-padded LDS,
// reg staging, ONE barrier per tile.  XCD-chunked: 64 consecutive blocks
// (4 (b,h) pairs, KV 2MB) per XCD -> K/V L2-resident.  Static-max softmax,
// permlane32_swap P redistribution, setprio on MFMA clusters.
constexpr int KB = 64;               // keys per tile
constexpr int KSLOT = 8 * 66;        // K granule-major [8][66] 16B slots
constexpr int VSLOT = 8 * 66;        // V^T granule-major [8][66]

__global__ __launch_bounds__(256) void attn_kernel(const short* __restrict__ qkv,
                                                   const short* __restrict__ vt,
                                                   const float* __restrict__ mbL,
                                                   short* __restrict__ att) {
  __shared__ short Kl[2][KSLOT * 8];   // 2 x 8.25 KB
  __shared__ short Vl[2][VSLOT * 8];   // 2 x 8.25 KB
  __shared__ float mb[SEQ];            // 8 KB mask bias (log2 domain, -8 shift)

  const int tid = threadIdx.x;
  const int w = tid >> 6, lane = tid & 63, ql = lane & 31, hi = lane >> 5;
  // XCD-chunked decode (512 blocks): xcd gets 64 consecutive ids.
  const int idx = blockIdx.x;
  const int swz = (idx & 7) * 64 + (idx >> 3);
  const int qb = swz & 15, h = (swz >> 4) & 15, b = swz >> 8;
  const int qrow = qb * 128 + w * 32 + ql;

  // ---- hoist Q fragments (B-operand: lane q holds Q[q][c*16 + hi*8 + j]) ----
  bf16x8 qf[4];
  {
    const short* qp = qkv + (size_t)(b * SEQ + qrow) * 3072 + h * 64;
    #pragma unroll
    for (int c = 0; c < 4; ++c)
      qf[c] = *reinterpret_cast<const bf16x8*>(qp + c * 16 + hi * 8);
  }

  // ---- staging maps (per-thread constants) ----
  const short* gkbase = qkv + (size_t)(b * SEQ) * 3072 + 1024 + h * 64
                        + (size_t)(tid >> 3) * 3072 + (tid & 7) * 8;
  const short* gvbase = vt + ((size_t)(b * 1024 + h * 64) + (tid >> 3)) * SEQ
                        + (tid & 7) * 8;
  short* kwr = &Kl[0][((tid & 7) * 66 + (tid >> 3)) * 8];
  short* vwr = &Vl[0][((tid & 7) * 66 + (tid >> 3)) * 8];

  u32x4 kreg0, kreg1, vreg0, vreg1;
  auto loadTile = [&](int kt) {
    const short* gk = gkbase + (size_t)kt * KB * 3072;
    kreg0 = *reinterpret_cast<const u32x4*>(gk);
    kreg1 = *reinterpret_cast<const u32x4*>(gk + 32 * 3072);
    const short* gv = gvbase + kt * KB;
    vreg0 = *reinterpret_cast<const u32x4*>(gv);
    vreg1 = *reinterpret_cast<const u32x4*>(gv + 32 * SEQ);
  };
  auto writeTile = [&](int buf) {
    short* kd = kwr + buf * KSLOT * 8;
    *reinterpret_cast<u32x4*>(kd)          = kreg0;   // compiler waits vmcnt here
    *reinterpret_cast<u32x4*>(kd + 32 * 8) = kreg1;
    short* vd = vwr + buf * VSLOT * 8;
    *reinterpret_cast<u32x4*>(vd)          = vreg0;
    *reinterpret_cast<u32x4*>(vd + 32 * 8) = vreg1;
  };

  float s_run = 0.f;
  f32x16 oacc0 = {}, oacc1 = {};

  // ---- prologue: mask bias (8KB, 2 gloads/thread) + tile 0 ----
  gload_lds16(mbL + b * SEQ + tid * 4, &mb[tid * 4]);
  gload_lds16(mbL + b * SEQ + 1024 + tid * 4, &mb[1024 + tid * 4]);
  loadTile(0);
  writeTile(0);
  __syncthreads();

  // per-lane LDS read bases (constant; reads use +imm offsets)
  const short* krd = &Kl[0][(hi * 66 + ql) * 8];
  const short* vrd = &Vl[0][(hi * 66 + ql) * 8];

  constexpr int NT = SEQ / KB;   // 32
  for (int kt = 0; kt < NT; ++kt) {
    const int cur = kt & 1;
    if (kt + 1 < NT) loadTile(kt + 1);   // HBM latency hides under compute(t)
    const short* Kb = krd + cur * KSLOT * 8;
    const short* Vb = vrd + cur * VSLOT * 8;

    #pragma unroll
    for (int t2 = 0; t2 < 2; ++t2) {
      // QK^T: S[k][q]
      f32x16 sc = {};
      __builtin_amdgcn_s_setprio(1);
      #pragma unroll
      for (int c = 0; c < 4; ++c) {
        bf16x8 kf = *reinterpret_cast<const bf16x8*>(Kb + (c * 132 + t2 * 32) * 8);
        sc = __builtin_amdgcn_mfma_f32_32x32x16_bf16(kf, qf[c], sc, 0, 0, 0);
      }
      __builtin_amdgcn_s_setprio(0);
      // p = exp2(score*scale*log2e + bias)   (bias = mask? -1.4e9 : -8)
      float p[16];
      #pragma unroll
      for (int u = 0; u < 4; ++u) {
        float4 m4 = *reinterpret_cast<const float4*>(&mb[kt * KB + t2 * 32 + u * 8 + hi * 4]);
        p[4 * u + 0] = EXP2(fmaf(sc[4 * u + 0], 0.18033688f, m4.x));   // 0.125*log2e
        p[4 * u + 1] = EXP2(fmaf(sc[4 * u + 1], 0.18033688f, m4.y));
        p[4 * u + 2] = EXP2(fmaf(sc[4 * u + 2], 0.18033688f, m4.z));
        p[4 * u + 3] = EXP2(fmaf(sc[4 * u + 3], 0.18033688f, m4.w));
      }
      // partial-sum tree (cross-lane deferred to epilogue)
      {
        float a0 = (p[0] + p[1]) + (p[2] + p[3]);
        float a1 = (p[4] + p[5]) + (p[6] + p[7]);
        float a2 = (p[8] + p[9]) + (p[10] + p[11]);
        float a3 = (p[12] + p[13]) + (p[14] + p[15]);
        s_run += (a0 + a1) + (a2 + a3);
      }
      // pack P -> bf16 pairs; permlane32_swap redistributes across half-waves
      unsigned P[8];
      #pragma unroll
      for (int j = 0; j < 8; ++j)
        asm("v_cvt_pk_bf16_f32 %0, %1, %2" : "=v"(P[j]) : "v"(p[2 * j]), "v"(p[2 * j + 1]));
      asm("v_permlane32_swap_b32 %0, %1" : "+v"(P[0]), "+v"(P[2]));
      asm("v_permlane32_swap_b32 %0, %1" : "+v"(P[1]), "+v"(P[3]));
      asm("v_permlane32_swap_b32 %0, %1" : "+v"(P[4]), "+v"(P[6]));
      asm("v_permlane32_swap_b32 %0, %1" : "+v"(P[5]), "+v"(P[7]));
      u32x4 c0 = { P[0], P[1], P[2], P[3] };
      u32x4 c1 = { P[4], P[5], P[6], P[7] };
      bf16x8 pf[2] = { __builtin_bit_cast(bf16x8, c0), __builtin_bit_cast(bf16x8, c1) };

      // PV: O^T[d][q] += V^T[d][k] P[k][q]
      __builtin_amdgcn_s_setprio(1);
      #pragma unroll
      for (int ch = 0; ch < 2; ++ch) {
        const int gb = (t2 * 4 + ch * 2) * 66;
        bf16x8 v0 = *reinterpret_cast<const bf16x8*>(Vb + gb * 8);
        bf16x8 v1 = *reinterpret_cast<const bf16x8*>(Vb + (gb + 32) * 8);
        oacc0 = __builtin_amdgcn_mfma_f32_32x32x16_bf16(v0, pf[ch], oacc0, 0, 0, 0);
        oacc1 = __builtin_amdgcn_mfma_f32_32x32x16_bf16(v1, pf[ch], oacc1, 0, 0, 0);
      }
      __builtin_amdgcn_s_setprio(0);
    }

    if (kt + 1 < NT) {
      writeTile(cur ^ 1);   // cur^1 readers finished at end of tile kt-1
      __syncthreads();      // writes visible before tile kt+1 reads
    }
  }

  // ---- epilogue: finish sum across half-waves, normalize, store ----
  const float sT = s_run + __shfl_xor(s_run, 32);
  const float inv = 1.f / sT;
  const size_t obase = (size_t)(b * SEQ + qrow) * 1024 + h * 64;
  #pragma unroll
  for (int dt = 0; dt < 2; ++dt) {
    #pragma unroll
    for (int u = 0; u < 4; ++u) {
      short4 st;
      const f32x16& oa = dt ? oacc1 : oacc0;
      st.x = f2bf(oa[4 * u + 0] * inv);
      st.y = f2bf(oa[4 * u + 1] * inv);
      st.z = f2bf(oa[4 * u + 2] * inv);
      st.w = f2bf(oa[4 * u + 3] * inv);
      *reinterpret_cast<short4*>(&att[obase + dt * 32 + u * 8 + hi * 4]) = st;
    }
  }
}

// -------------------------- residual + LayerNorm ----------------------------
// Vectorized: thread t handles cols 4t..4t+3 (float4 / short4 loads).
__global__ __launch_bounds__(256) void ln_kernel(const float* __restrict__ h,
                                                 const short* __restrict__ ao,
                                                 const short* __restrict__ gl,
                                                 const float* __restrict__ gamma,
                                                 const float* __restrict__ beta,
                                                 float* __restrict__ out) {
  const int row = blockIdx.x;
  const size_t base = (size_t)row * 1024;
  const int t = threadIdx.x;
  __shared__ float red[4];
  float4 x = reinterpret_cast<const float4*>(h + base)[t];
  const short4 a4 = reinterpret_cast<const short4*>(ao + base)[t];
  const short4 g4 = reinterpret_cast<const short4*>(gl + base)[t];
  x.x += bf2f(a4.x) + bf2f(g4.x);
  x.y += bf2f(a4.y) + bf2f(g4.y);
  x.z += bf2f(a4.z) + bf2f(g4.z);
  x.w += bf2f(a4.w) + bf2f(g4.w);
  float s = (x.x + x.y) + (x.z + x.w);
  #pragma unroll
  for (int d = 1; d < 64; d <<= 1) s += __shfl_xor(s, d);
  if ((t & 63) == 0) red[t >> 6] = s;
  __syncthreads();
  const float mu = (red[0] + red[1] + red[2] + red[3]) * (1.f / 1024.f);
  __syncthreads();
  const float dx0 = x.x - mu, dx1 = x.y - mu, dx2 = x.z - mu, dx3 = x.w - mu;
  float vs = (dx0 * dx0 + dx1 * dx1) + (dx2 * dx2 + dx3 * dx3);
  #pragma unroll
  for (int d = 1; d < 64; d <<= 1) vs += __shfl_xor(vs, d);
  if ((t & 63) == 0) red[t >> 6] = vs;
  __syncthreads();
  const float var = (red[0] + red[1] + red[2] + red[3]) * (1.f / 1024.f);
  const float rs = rsqrtf(var + 1e-6f);
  const float4 gm = reinterpret_cast<const float4*>(gamma)[t];
  const float4 bt = reinterpret_cast<const float4*>(beta)[t];
  float4 o;
  o.x = dx0 * rs * gm.x + bt.x;
  o.y = dx1 * rs * gm.y + bt.y;
  o.z = dx2 * rs * gm.z + bt.z;
  o.w = dx3 * rs * gm.w + bt.w;
  reinterpret_cast<float4*>(out + base)[t] = o;
}

// ------------------------------- launcher ----------------------------------

extern "C" void kernel_launch(void* const* d_in, const int* in_sizes, int n_in,
                              void* d_out, int out_size, void* d_ws, size_t ws_size,
                              hipStream_t stream) {
  const float* h   = (const float*)d_in[0];
  const void*  msk = d_in[1];
  const float* Wq  = (const float*)d_in[2];
  const float* bq  = (const float*)d_in[3];
  const float* Wkv = (const float*)d_in[4];
  const float* bkv = (const float*)d_in[5];
  const float* Wo  = (const float*)d_in[6];
  const float* bo  = (const float*)d_in[7];
  const float* W1  = (const float*)d_in[8];
  const float* b1  = (const float*)d_in[9];
  const float* W2  = (const float*)d_in[10];
  const float* b2  = (const float*)d_in[11];
  const float* lng = (const float*)d_in[12];
  const float* lnb = (const float*)d_in[13];
  float* out = (float*)d_out;

  char* ws = (char*)d_ws;
  size_t off = 0;
  auto alloc = [&](size_t bytes) {
    char* p = ws + off;
    off += (bytes + 255) & ~(size_t)255;
    return p;
  };
  short* X     = (short*)alloc((size_t)MROWS * 1024 * 2);   // h in bf16
  short* WALL  = (short*)alloc((size_t)5120 * 1024 * 2);    // [Wq|Wkv|W1/W2 ilv]^T
  short* WoT   = (short*)alloc((size_t)1024 * 1024 * 2);
  float* ball  = (float*)alloc(5120 * 4);
  float* MBL   = (float*)alloc((size_t)MROWS * 4);          // mask bias (log2 dom)
  short* QKV   = (short*)alloc((size_t)MROWS * 3072 * 2);   // Q,K rows (V unused)
  short* VT    = (short*)alloc((size_t)BATCH * 1024 * SEQ * 2);  // V transposed
  short* ATT   = (short*)alloc((size_t)MROWS * 1024 * 2);
  short* X1    = (short*)alloc((size_t)MROWS * 1024 * 2);   // GLU result bf16
  short* AO    = (short*)alloc((size_t)MROWS * 1024 * 2);   // attention proj bf16
  if (off > ws_size) return;  // workspace too small: bail visibly

  cvt_bf16<<<4096, 256, 0, stream>>>(h, X, MROWS * 1024 / 4);
  WtA wa;
  wa.s[0] = Wq;          wa.d[0] = WALL;                wa.st[0] = 1024;  wa.mul[0] = 1; wa.add[0] = 0;
  wa.s[1] = Wkv;         wa.d[1] = WALL + 1024 * 1024;  wa.st[1] = 2048;  wa.mul[1] = 1; wa.add[1] = 0;
  wa.s[2] = Wkv + 1024;  wa.d[2] = WALL + 2048 * 1024;  wa.st[2] = 2048;  wa.mul[2] = 1; wa.add[2] = 0;
  wa.s[3] = Wo;          wa.d[3] = WoT;                 wa.st[3] = 1024;  wa.mul[3] = 1; wa.add[3] = 0;
  wa.s[4] = W1;          wa.d[4] = WALL + 3072 * 1024;  wa.st[4] = 1024;  wa.mul[4] = 2; wa.add[4] = 0;
  wa.s[5] = W2;          wa.d[5] = WALL + 3072 * 1024;  wa.st[5] = 1024;  wa.mul[5] = 2; wa.add[5] = 1;
  wtrans6<<<dim3(32, 32, 6), 256, 0, stream>>>(wa);
  pack_bias<<<16, 256, 0, stream>>>(bq, bkv, b1, b2, ball);
  premask<<<16, 256, 0, stream>>>(msk, MBL);

  // fused QKV + GLU projection (V written transposed; vtrans eliminated)
  gemm_qkvglu<<<1280, 256, 0, stream>>>(X, WALL, ball, QKV, VT, X1);
  // flash attention, full-K per block (merge eliminated) -> ATT normalized
  attn_kernel<<<512, 256, 0, stream>>>(QKV, VT, MBL, ATT);
  // attention out projection: BN=64 tile -> 512 blocks (2/CU)
  gemm_bf16<64><<<dim3(16, 32), 256, 0, stream>>>(ATT, WoT, bo, AO, 1024);
  // out = LayerNorm(h + AO + X1)
  ln_kernel<<<MROWS, 256, 0, stream>>>(h, AO, X1, lng, lnb, out);
}